// Round 7
// baseline (3066.851 us; speedup 1.0000x reference)
//
#include <hip/hip_runtime.h>
#include <hip/hip_bf16.h>
#include <math.h>

#define TT 256
#define BB 256
#define DP1 129
#define HH 512
#define K1 1280
#define DD 128
#define RTOT 65280   // B*(T-1)
#define XKP 144      // padded x-part K (129 feats + 1 bias + 14 zero)
#define HKP 528      // padded h-part K (512 h + 1 bias@512 + td@513 + zeros)

// ---- ws layout: all bf16, base = (bf16*)ws ----
#define U_X16   0            // 65536*144
#define U_WHF   9437184      // 48*33*512
#define U_WXF   10248192     // 48*9*512
#define U_H0    10469376     // 256*528
#define U_BAR   10604544     // (dead slot kept for branch arithmetic)
#define U_W1P   10604800     // 40 tiles * 33 kc * 512   (K=528, cols 1280)
#define U_W2P   11280640     // 4 tiles * 80 kc * 512    (K=1280, cols 128)
#define U_HIST  11444480     // 256*256*528
#define U_FLAGS 46047488     // 512 ints (8 groups x 64-int stride)
#define PREP_N  12494080     // total prep work items
// out layout (floats)
#define OUT_DIST 8355840     // 256*255*128
#define OUT_LEN  8356608

typedef __attribute__((ext_vector_type(8))) short bf16x8;
typedef __attribute__((ext_vector_type(16))) float f32x16;

__device__ __forceinline__ float sigm(float v) { return 1.0f / (1.0f + __expf(-v)); }

__device__ __forceinline__ unsigned short bfbits(float f) {
    union { __hip_bfloat16 h; unsigned short u; } cv;
    cv.h = __float2bfloat16(f);
    return cv.u;
}

// One-time pack: bf16 x (+bias col), GRU weights as MFMA B-frags (biases folded
// as constant-1 K rows), h0, head weights as MFMA B-frags, hist pad columns
// (constant per step -> written once here), and flag init.
__global__ __launch_bounds__(256) void prep_kernel(
    const float* __restrict__ x, const float* __restrict__ h0,
    const float* __restrict__ w_ih, const float* __restrict__ w_hh,
    const float* __restrict__ b_ih, const float* __restrict__ b_hh,
    const float* __restrict__ w1, const float* __restrict__ b1,
    const float* __restrict__ w2,
    __hip_bfloat16* __restrict__ bf)
{
    int i = blockIdx.x * 256 + threadIdx.x;
    if (i < 9437184) {                        // x16: (t*B+b, 144)
        int tb = i / XKP, k = i - tb * XKP;
        float v = (k < DP1) ? x[(size_t)tb * DP1 + k] : (k == DP1 ? 1.0f : 0.0f);
        bf[U_X16 + i] = __float2bfloat16(v);
    } else if (i < 10248192) {                // whf B-frags (K=528 incl b_hh row)
        int r = i - 9437184;
        int e = r & 7;
        int lane = (r >> 3) & 63;
        int rem = r >> 9;
        int kc = rem % 33, gi = rem / 33;
        int jb = gi / 3, g = gi - jb * 3;
        int j = jb * 32 + (lane & 31);
        int k = kc * 16 + (lane >> 5) * 8 + e;
        float v = (k < HH) ? w_hh[(size_t)(g * HH + j) * HH + k]
                : (k == HH ? b_hh[g * HH + j] : 0.0f);
        bf[U_WHF + r] = __float2bfloat16(v);
    } else if (i < 10469376) {                // wxf B-frags (K=144 incl b_ih row)
        int r = i - 10248192;
        int e = r & 7;
        int lane = (r >> 3) & 63;
        int rem = r >> 9;
        int kc = rem % 9, gi = rem / 9;
        int jb = gi / 3, g = gi - jb * 3;
        int j = jb * 32 + (lane & 31);
        int k = kc * 16 + (lane >> 5) * 8 + e;
        float v = (k < DP1) ? w_ih[(size_t)(g * HH + j) * DP1 + k]
                : (k == DP1 ? b_ih[g * HH + j] : 0.0f);
        bf[U_WXF + r] = __float2bfloat16(v);
    } else if (i < 10604544) {                // h0 padded (B, 528)
        int r = i - 10469376;
        int b = r / HKP, k = r - b * HKP;
        float v = (k < HH) ? h0[(size_t)b * HH + k] : (k == HH ? 1.0f : 0.0f);
        bf[U_H0 + r] = __float2bfloat16(v);
    } else if (i < 10604800) {                // dead region (kept zeroed)
        bf[U_BAR + (i - 10604544)] = __float2bfloat16(0.0f);
    } else if (i < 11280640) {                // w1p B-frags (40 tiles, 33 kc)
        int r = i - 10604800;
        int e = r & 7;
        int lane = (r >> 3) & 63;
        int rem = r >> 9;
        int kc = rem % 33, tile = rem / 33;
        int col = tile * 32 + (lane & 31);
        int k = kc * 16 + (lane >> 5) * 8 + e;
        float v = (k < HH) ? w1[(size_t)col * 513 + k]
                : (k == HH ? b1[col]
                : (k == HH + 1 ? w1[(size_t)col * 513 + 512] : 0.0f));
        bf[U_W1P + r] = __float2bfloat16(v);
    } else if (i < 11444480) {                // w2p B-frags (4 tiles, 80 kc)
        int r = i - 11280640;
        int e = r & 7;
        int lane = (r >> 3) & 63;
        int rem = r >> 9;
        int kc = rem % 80, tile = rem / 80;
        int col = tile * 32 + (lane & 31);
        int k = kc * 16 + (lane >> 5) * 8 + e;
        bf[U_W2P + r] = __float2bfloat16(w2[(size_t)col * K1 + k]);
    } else if (i < 12493056) {                // hist pad cols 512..527, all (t,b)
        int idx = i - 11444480;
        int row = idx >> 4, c = idx & 15;
        bf[U_HIST + (size_t)row * HKP + HH + c] =
            __float2bfloat16(c == 0 ? 1.0f : 0.0f);
    } else if (i < PREP_N) {                  // zero flags (ws is re-poisoned!)
        int idx = i - 12493056;
        if (idx < 512) ((int*)(bf + U_FLAGS))[idx] = 0;
    }
}

// Persistent GRU scan. Grid (8 bt, 16 jblk) = 128 blocks, 256 thr, all
// co-resident. Waves 0/1/2 = gates r/z/n, B-frags in registers; h carry in
// registers. Cross-block sync per step (PROVEN round-5 semantics, parallelized):
//   writer: __syncthreads (drains stores to L2) -> tid0: __threadfence
//           (wbl2: XCD-L2 writeback, covers ALL threads' h stores) -> relaxed
//           agent flag store (per-block flag, no serialized RMW chain).
//   reader: wave 3 polls the 16 group flags (coalesced), then __threadfence
//           (inv: drop stale L1/L2 lines) -> __syncthreads.
// During the wait, waves 0-2 prefetch x A-frags for t+1 AND pre-compute the
// x-part MFMAs (h-independent), removing them from the serial path.
__global__ __launch_bounds__(256, 1) void gru_scan(
    const __hip_bfloat16* __restrict__ x16,
    const __hip_bfloat16* __restrict__ h0p,
    __hip_bfloat16* __restrict__ hist,
    const __hip_bfloat16* __restrict__ whf,
    const __hip_bfloat16* __restrict__ wxf,
    const int* __restrict__ lengths,
    int* __restrict__ flags)
{
    __shared__ float p[4][32][33];
    const int tid  = threadIdx.x;
    const int bt   = blockIdx.x;
    const int jblk = blockIdx.y;
    const int b0   = bt * 32;
    const int wid  = tid >> 6;
    const int ln   = tid & 63;
    const int row  = b0 + (ln & 31);
    const int khi  = (ln >> 5) * 8;
    int* myflag = flags + bt * 64 + jblk;

    // B fragments -> registers, once.
    bf16x8 bh[33], bx[9];
    if (wid < 3) {
        const bf16x8* bH = (const bf16x8*)whf + ((jblk * 3 + wid) * 33) * 64 + ln;
        #pragma unroll
        for (int kc = 0; kc < 33; ++kc) bh[kc] = bH[kc * 64];
        const bf16x8* bX = (const bf16x8*)wxf + ((jblk * 3 + wid) * 9) * 64 + ln;
        #pragma unroll
        for (int kc = 0; kc < 9; ++kc) bx[kc] = bX[kc * 64];
    }

    // Epilogue mapping: row br = tid>>3; cols j0 = 2*((tid&7)+8i), i in {0,1}.
    const int br = tid >> 3;
    const int lenb = lengths[b0 + br];
    float hreg[2][2];
    #pragma unroll
    for (int i = 0; i < 2; ++i) {
        int gj = jblk * 32 + 2 * ((tid & 7) + 8 * i);
        hreg[i][0] = __bfloat162float(h0p[(size_t)(b0 + br) * HKP + gj]);
        hreg[i][1] = __bfloat162float(h0p[(size_t)(b0 + br) * HKP + gj + 1]);
    }

    // x A-frags for t=0 + pre-computed x-part accumulator
    bf16x8 ax[9];
    f32x16 accX = {};
    if (wid < 3) {
        const bf16x8* aX = (const bf16x8*)(x16 + (size_t)row * XKP + khi);
        #pragma unroll
        for (int kc = 0; kc < 9; ++kc) ax[kc] = aX[kc * 2];
        #pragma unroll
        for (int kc = 0; kc < 9; ++kc)
            accX = __builtin_amdgcn_mfma_f32_32x32x16_bf16(ax[kc], bx[kc], accX, 0, 0, 0);
    }

    for (int t = 0; t < TT; ++t) {
        const __hip_bfloat16* hprev = (t == 0) ? h0p : (hist + (size_t)(t - 1) * BB * HKP);
        __hip_bfloat16* hout = hist + (size_t)t * BB * HKP;

        if (wid < 3) {
            f32x16 accHa = {}, accHb = {};
            const bf16x8* aH = (const bf16x8*)(hprev + (size_t)row * HKP + khi);
            #pragma unroll
            for (int kc = 0; kc < 32; kc += 2) {
                accHa = __builtin_amdgcn_mfma_f32_32x32x16_bf16(aH[kc * 2], bh[kc], accHa, 0, 0, 0);
                accHb = __builtin_amdgcn_mfma_f32_32x32x16_bf16(aH[(kc + 1) * 2], bh[kc + 1], accHb, 0, 0, 0);
            }
            accHa = __builtin_amdgcn_mfma_f32_32x32x16_bf16(aH[32 * 2], bh[32], accHa, 0, 0, 0);

            const int col = ln & 31;
            const int rh = 4 * (ln >> 5);
            if (wid < 2) {
                f32x16 s = accHa + accHb + accX;
                #pragma unroll
                for (int r = 0; r < 16; ++r)
                    p[wid][(r & 3) + 8 * (r >> 2) + rh][col] = s[r];
            } else {
                f32x16 sh = accHa + accHb;
                #pragma unroll
                for (int r = 0; r < 16; ++r) {
                    int rr = (r & 3) + 8 * (r >> 2) + rh;
                    p[2][rr][col] = accX[r];   // xn (+ b_ih_n)
                    p[3][rr][col] = sh[r];     // hn (+ b_hh_n)
                }
            }
        }
        __syncthreads();

        {   // gate epilogue: carry in registers, normal stores (L2)
            const bool valid = (t < lenb);
            #pragma unroll
            for (int i = 0; i < 2; ++i) {
                int j0 = 2 * ((tid & 7) + 8 * i);
                float rr0 = sigm(p[0][br][j0]);
                float zz0 = sigm(p[1][br][j0]);
                float nn0 = tanhf(p[2][br][j0] + rr0 * p[3][br][j0]);
                float h0v = valid ? ((1.f - zz0) * nn0 + zz0 * hreg[i][0]) : hreg[i][0];
                float rr1 = sigm(p[0][br][j0 + 1]);
                float zz1 = sigm(p[1][br][j0 + 1]);
                float nn1 = tanhf(p[2][br][j0 + 1] + rr1 * p[3][br][j0 + 1]);
                float h1v = valid ? ((1.f - zz1) * nn1 + zz1 * hreg[i][1]) : hreg[i][1];
                hreg[i][0] = h0v;
                hreg[i][1] = h1v;
                unsigned uv = (unsigned)bfbits(h0v) | ((unsigned)bfbits(h1v) << 16);
                *(unsigned*)(hout + (size_t)(b0 + br) * HKP + jblk * 32 + j0) = uv;
            }
        }
        __syncthreads();              // compiler drains vmcnt before s_barrier

        if (t < TT - 1) {
            if (tid == 0) {
                __threadfence();      // wbl2: push XCD-L2 dirty lines (all h stores)
                __hip_atomic_store(myflag, t + 1, __ATOMIC_RELAXED, __HIP_MEMORY_SCOPE_AGENT);
            }
            if (wid < 3) {
                // overlap: prefetch x A-frags for t+1 and pre-compute x-part MFMAs
                const bf16x8* aX = (const bf16x8*)(x16 + ((size_t)(t + 1) * BB + row) * XKP + khi);
                #pragma unroll
                for (int kc = 0; kc < 9; ++kc) ax[kc] = aX[kc * 2];
                f32x16 aXn = {};
                #pragma unroll
                for (int kc = 0; kc < 9; ++kc)
                    aXn = __builtin_amdgcn_mfma_f32_32x32x16_bf16(ax[kc], bx[kc], aXn, 0, 0, 0);
                accX = aXn;
            }
            if (wid == 3) {           // idle wave polls the 16 group flags
                const int* f = flags + bt * 64 + (ln & 15);
                while (true) {
                    int v = __hip_atomic_load(f, __ATOMIC_RELAXED, __HIP_MEMORY_SCOPE_AGENT);
                    if (__all(v >= t + 1)) break;
                    __builtin_amdgcn_s_sleep(1);
                }
                __threadfence();      // acquire: invalidate stale L1/L2 lines
            }
            __syncthreads();
        }
    }
}

// Write td into hist col 513 (after the scan) so the head's stage-1 is a pure
// K=528 GEMM over hist rows.
__global__ __launch_bounds__(256) void td_kernel(
    const float* __restrict__ x, __hip_bfloat16* __restrict__ hist)
{
    int r = blockIdx.x * 256 + threadIdx.x;
    if (r < RTOT) {
        int b = r / 255, t = r - b * 255;
        float td = x[((size_t)(t + 1) * BB + b) * DP1] - x[((size_t)t * BB + b) * DP1];
        hist[((size_t)t * BB + b) * HKP + 513] = __float2bfloat16(td);
    }
}

// MFMA head: block = 64 rows (2 row-tiles) x 4 waves, 1020 blocks.
__global__ __launch_bounds__(256) void head_mfma(
    const __hip_bfloat16* __restrict__ hist,
    const __hip_bfloat16* __restrict__ w1p,
    const __hip_bfloat16* __restrict__ w2p,
    const float* __restrict__ b2,
    const int* __restrict__ lengths,
    float* __restrict__ out)
{
    __shared__ __hip_bfloat16 preS[64 * 264];
    const int tid = threadIdx.x;
    const int wv  = tid >> 6;
    const int ln  = tid & 63;
    const int r0  = blockIdx.x * 64;
    const int m   = ln & 31;
    const int khi = (ln >> 5) * 8;

    const __hip_bfloat16* aBase0;
    const __hip_bfloat16* aBase1;
    {
        int r = r0 + m;
        int b = r / 255, t = r - b * 255;
        aBase0 = hist + ((size_t)t * BB + b) * HKP + khi;
        r = r0 + 32 + m;
        b = r / 255; t = r - b * 255;
        aBase1 = hist + ((size_t)t * BB + b) * HKP + khi;
    }

    f32x16 acc20 = {}, acc21 = {};

    for (int c = 0; c < 5; ++c) {
        f32x16 s00 = {}, s01 = {}, s10 = {}, s11 = {};
        const int t0 = c * 8 + wv * 2;
        const bf16x8* bp0 = (const bf16x8*)w1p + ((size_t)t0 * 33) * 64 + ln;
        const bf16x8* bp1 = bp0 + 33 * 64;
        #pragma unroll 4
        for (int kc = 0; kc < 33; ++kc) {
            bf16x8 a0 = *(const bf16x8*)(aBase0 + kc * 16);
            bf16x8 a1 = *(const bf16x8*)(aBase1 + kc * 16);
            bf16x8 w0 = bp0[kc * 64];
            bf16x8 w1f = bp1[kc * 64];
            s00 = __builtin_amdgcn_mfma_f32_32x32x16_bf16(a0, w0, s00, 0, 0, 0);
            s01 = __builtin_amdgcn_mfma_f32_32x32x16_bf16(a0, w1f, s01, 0, 0, 0);
            s10 = __builtin_amdgcn_mfma_f32_32x32x16_bf16(a1, w0, s10, 0, 0, 0);
            s11 = __builtin_amdgcn_mfma_f32_32x32x16_bf16(a1, w1f, s11, 0, 0, 0);
        }
        const int colL = wv * 64 + m;
        const int rb = 4 * (ln >> 5);
        #pragma unroll
        for (int reg = 0; reg < 16; ++reg) {
            int rr = (reg & 3) + 8 * (reg >> 2) + rb;
            preS[rr * 264 + colL]             = __float2bfloat16(sigm(s00[reg]));
            preS[rr * 264 + colL + 32]        = __float2bfloat16(sigm(s01[reg]));
            preS[(rr + 32) * 264 + colL]      = __float2bfloat16(sigm(s10[reg]));
            preS[(rr + 32) * 264 + colL + 32] = __float2bfloat16(sigm(s11[reg]));
        }
        __syncthreads();

        const bf16x8* b2p = (const bf16x8*)w2p + ((size_t)wv * 80 + c * 16) * 64 + ln;
        #pragma unroll 4
        for (int j = 0; j < 16; ++j) {
            bf16x8 pa0 = *(const bf16x8*)(preS + m * 264 + j * 16 + khi);
            bf16x8 pa1 = *(const bf16x8*)(preS + (32 + m) * 264 + j * 16 + khi);
            bf16x8 wb = b2p[j * 64];
            acc20 = __builtin_amdgcn_mfma_f32_32x32x16_bf16(pa0, wb, acc20, 0, 0, 0);
            acc21 = __builtin_amdgcn_mfma_f32_32x32x16_bf16(pa1, wb, acc21, 0, 0, 0);
        }
        __syncthreads();
    }

    const int d = wv * 32 + m;
    const float bias = b2[d];
    const int rb = 4 * (ln >> 5);
    #pragma unroll
    for (int reg = 0; reg < 16; ++reg) {
        int rr = (reg & 3) + 8 * (reg >> 2) + rb;
        {
            int r = r0 + rr;
            int b = r / 255, t = r - b * 255;
            bool valid = t < (lengths[b] - 1);
            out[(size_t)r * DD + d] = valid ? (acc20[reg] + bias) : 0.f;
        }
        {
            int r = r0 + 32 + rr;
            int b = r / 255, t = r - b * 255;
            bool valid = t < (lengths[b] - 1);
            out[(size_t)r * DD + d] = valid ? (acc21[reg] + bias) : 0.f;
        }
    }
}

__global__ __launch_bounds__(256) void tail_kernel(
    const __hip_bfloat16* __restrict__ hist,
    const float* __restrict__ wp,
    const float* __restrict__ bp,
    const int* __restrict__ lengths,
    float* __restrict__ out)
{
    int gid = blockIdx.x * 256 + threadIdx.x;
    if (gid < 768) {
        int b = gid / 3, pidx = gid - b * 3;
        float acc = bp[pidx];
        const __hip_bfloat16* hr = hist + ((size_t)(TT - 1) * BB + b) * HKP;
        const float* wr = wp + (size_t)pidx * HH;
        #pragma unroll 4
        for (int k = 0; k < HH; ++k) acc += __bfloat162float(hr[k]) * wr[k];
        out[OUT_DIST + gid] = __expf(-acc);
    } else if (gid < 1024) {
        int b = gid - 768;
        out[OUT_LEN + b] = (float)lengths[b];
    }
}

extern "C" void kernel_launch(void* const* d_in, const int* in_sizes, int n_in,
                              void* d_out, int out_size, void* d_ws, size_t ws_size,
                              hipStream_t stream)
{
    const float* x       = (const float*)d_in[0];
    const float* h0      = (const float*)d_in[1];
    const int*   lengths = (const int*)d_in[2];
    const float* w_ih    = (const float*)d_in[3];
    const float* w_hh    = (const float*)d_in[4];
    const float* b_ih    = (const float*)d_in[5];
    const float* b_hh    = (const float*)d_in[6];
    const float* w1      = (const float*)d_in[7];
    const float* b1      = (const float*)d_in[8];
    const float* w2      = (const float*)d_in[9];
    const float* b2      = (const float*)d_in[10];
    const float* wp      = (const float*)d_in[11];
    const float* bp      = (const float*)d_in[12];
    float* out = (float*)d_out;

    __hip_bfloat16* bf   = (__hip_bfloat16*)d_ws;
    __hip_bfloat16* x16  = bf + U_X16;
    __hip_bfloat16* whf  = bf + U_WHF;
    __hip_bfloat16* wxf  = bf + U_WXF;
    __hip_bfloat16* h16i = bf + U_H0;
    __hip_bfloat16* w1p  = bf + U_W1P;
    __hip_bfloat16* w2p  = bf + U_W2P;
    __hip_bfloat16* hist = bf + U_HIST;
    int* flags           = (int*)(bf + U_FLAGS);

    prep_kernel<<<PREP_N / 256, 256, 0, stream>>>(
        x, h0, w_ih, w_hh, b_ih, b_hh, w1, b1, w2, bf);

    gru_scan<<<dim3(8, 16), 256, 0, stream>>>(x16, h16i, hist, whf, wxf, lengths, flags);

    td_kernel<<<(RTOT + 255) / 256, 256, 0, stream>>>(x, hist);

    head_mfma<<<RTOT / 64, 256, 0, stream>>>(hist, w1p, w2p, b2, lengths, out);

    tail_kernel<<<4, 256, 0, stream>>>(hist, wp, bp, lengths, out);
}

// Round 8
// 2146.107 us; speedup vs baseline: 1.4290x; 1.4290x over previous
//
#include <hip/hip_runtime.h>
#include <hip/hip_bf16.h>
#include <math.h>

#define TT 256
#define BB 256
#define DP1 129
#define HH 512
#define K1 1280
#define DD 128
#define RTOT 65280   // B*(T-1)
#define XKP 144      // padded x-part K (129 feats + 1 bias + 14 zero)
#define HKP 528      // padded h-part K (512 h + 1 bias@512 + td@513 + zeros)

// ---- ws layout: all bf16, base = (bf16*)ws ----
#define U_X16   0            // 65536*144
#define U_WHF   9437184      // 48*33*512
#define U_WXF   10248192     // 48*9*512
#define U_H0    10469376     // 256*528
#define U_BAR   10604544     // negotiation scratch: 16 ints (zeroed each launch)
#define U_W1P   10604800     // 40 tiles * 33 kc * 512   (K=528, cols 1280)
#define U_W2P   11280640     // 4 tiles * 80 kc * 512    (K=1280, cols 128)
#define U_HIST  11444480     // 256*256*528
#define U_FLAGS 46047488     // 512 ints (8 groups x 64-int stride)
#define PREP_N  12494080     // total prep work items
// out layout (floats)
#define OUT_DIST 8355840     // 256*255*128
#define OUT_LEN  8356608

typedef __attribute__((ext_vector_type(8))) short bf16x8;
typedef __attribute__((ext_vector_type(16))) float f32x16;

__device__ __forceinline__ float sigm(float v) { return 1.0f / (1.0f + __expf(-v)); }

__device__ __forceinline__ unsigned short bfbits(float f) {
    union { __hip_bfloat16 h; unsigned short u; } cv;
    cv.h = __float2bfloat16(f);
    return cv.u;
}

// One-time pack: bf16 x (+bias col), GRU weights as MFMA B-frags (biases folded
// as constant-1 K rows), h0, head weights as MFMA B-frags, hist pad columns
// (constant per step -> written once here), negotiation scratch + flag init.
__global__ __launch_bounds__(256) void prep_kernel(
    const float* __restrict__ x, const float* __restrict__ h0,
    const float* __restrict__ w_ih, const float* __restrict__ w_hh,
    const float* __restrict__ b_ih, const float* __restrict__ b_hh,
    const float* __restrict__ w1, const float* __restrict__ b1,
    const float* __restrict__ w2,
    __hip_bfloat16* __restrict__ bf)
{
    int i = blockIdx.x * 256 + threadIdx.x;
    if (i < 9437184) {                        // x16: (t*B+b, 144)
        int tb = i / XKP, k = i - tb * XKP;
        float v = (k < DP1) ? x[(size_t)tb * DP1 + k] : (k == DP1 ? 1.0f : 0.0f);
        bf[U_X16 + i] = __float2bfloat16(v);
    } else if (i < 10248192) {                // whf B-frags (K=528 incl b_hh row)
        int r = i - 9437184;
        int e = r & 7;
        int lane = (r >> 3) & 63;
        int rem = r >> 9;
        int kc = rem % 33, gi = rem / 33;
        int jb = gi / 3, g = gi - jb * 3;
        int j = jb * 32 + (lane & 31);
        int k = kc * 16 + (lane >> 5) * 8 + e;
        float v = (k < HH) ? w_hh[(size_t)(g * HH + j) * HH + k]
                : (k == HH ? b_hh[g * HH + j] : 0.0f);
        bf[U_WHF + r] = __float2bfloat16(v);
    } else if (i < 10469376) {                // wxf B-frags (K=144 incl b_ih row)
        int r = i - 10248192;
        int e = r & 7;
        int lane = (r >> 3) & 63;
        int rem = r >> 9;
        int kc = rem % 9, gi = rem / 9;
        int jb = gi / 3, g = gi - jb * 3;
        int j = jb * 32 + (lane & 31);
        int k = kc * 16 + (lane >> 5) * 8 + e;
        float v = (k < DP1) ? w_ih[(size_t)(g * HH + j) * DP1 + k]
                : (k == DP1 ? b_ih[g * HH + j] : 0.0f);
        bf[U_WXF + r] = __float2bfloat16(v);
    } else if (i < 10604544) {                // h0 padded (B, 528)
        int r = i - 10469376;
        int b = r / HKP, k = r - b * HKP;
        float v = (k < HH) ? h0[(size_t)b * HH + k] : (k == HH ? 1.0f : 0.0f);
        bf[U_H0 + r] = __float2bfloat16(v);
    } else if (i < 10604800) {                // zero negotiation scratch
        bf[U_BAR + (i - 10604544)] = __float2bfloat16(0.0f);
    } else if (i < 11280640) {                // w1p B-frags (40 tiles, 33 kc)
        int r = i - 10604800;
        int e = r & 7;
        int lane = (r >> 3) & 63;
        int rem = r >> 9;
        int kc = rem % 33, tile = rem / 33;
        int col = tile * 32 + (lane & 31);
        int k = kc * 16 + (lane >> 5) * 8 + e;
        float v = (k < HH) ? w1[(size_t)col * 513 + k]
                : (k == HH ? b1[col]
                : (k == HH + 1 ? w1[(size_t)col * 513 + 512] : 0.0f));
        bf[U_W1P + r] = __float2bfloat16(v);
    } else if (i < 11444480) {                // w2p B-frags (4 tiles, 80 kc)
        int r = i - 11280640;
        int e = r & 7;
        int lane = (r >> 3) & 63;
        int rem = r >> 9;
        int kc = rem % 80, tile = rem / 80;
        int col = tile * 32 + (lane & 31);
        int k = kc * 16 + (lane >> 5) * 8 + e;
        bf[U_W2P + r] = __float2bfloat16(w2[(size_t)col * K1 + k]);
    } else if (i < 12493056) {                // hist pad cols 512..527, all (t,b)
        int idx = i - 11444480;
        int row = idx >> 4, c = idx & 15;
        bf[U_HIST + (size_t)row * HKP + HH + c] =
            __float2bfloat16(c == 0 ? 1.0f : 0.0f);
    } else if (i < PREP_N) {                  // zero flags (ws is re-poisoned!)
        int idx = i - 12493056;
        if (idx < 512) ((int*)(bf + U_FLAGS))[idx] = 0;
    }
}

// Persistent GRU scan. Grid (8 bt, 16 jblk) = 128 blocks, 256 thr, all
// co-resident. Waves 0/1/2 = gates r/z/n, B-frags + h carry in registers.
//
// Cross-block sync per step, two verified-correct paths selected at runtime:
//  * FAST (group's 16 blocks all on ONE XCD, detected via HW_REG_XCC_ID +
//    LLC mask exchange): writer __syncthreads drains h stores into the shared
//    XCD-L2; flag via agent-scope atomic (LLC); reader polls flags then
//    __syncthreads — NO threadfence (same-L2 coherence; h addresses are
//    first-touch each step so L1 staleness is impossible).
//  * SLOW (group spans XCDs — mapping is undefined, G16): round-7 protocol,
//    __threadfence release/acquire around the same flags. Correct under any
//    workgroup->XCD assignment.
__global__ __launch_bounds__(256, 1) void gru_scan(
    const __hip_bfloat16* __restrict__ x16,
    const __hip_bfloat16* __restrict__ h0p,
    __hip_bfloat16* __restrict__ hist,
    const __hip_bfloat16* __restrict__ whf,
    const __hip_bfloat16* __restrict__ wxf,
    const int* __restrict__ lengths,
    int* __restrict__ flags,
    int* __restrict__ nego)
{
    __shared__ float p[4][32][33];
    __shared__ int fastS;
    const int tid  = threadIdx.x;
    const int bt   = blockIdx.x;
    const int jblk = blockIdx.y;
    const int b0   = bt * 32;
    const int wid  = tid >> 6;
    const int ln   = tid & 63;
    const int row  = b0 + (ln & 31);
    const int khi  = (ln >> 5) * 8;
    int* myflag = flags + bt * 64 + jblk;

    // --- one-time group topology negotiation (through LLC) ---
    if (tid == 0) {
        int xcc = 0;
        asm volatile("s_getreg_b32 %0, hwreg(HW_REG_XCC_ID, 0, 32)" : "=s"(xcc));
        atomicOr(nego + bt, 1 << (xcc & 7));
        __threadfence();                       // order OR before arrive
        atomicAdd(nego + 8 + bt, 1);
        while (__hip_atomic_load(nego + 8 + bt, __ATOMIC_RELAXED,
                                 __HIP_MEMORY_SCOPE_AGENT) < 16)
            __builtin_amdgcn_s_sleep(1);
        int m = __hip_atomic_load(nego + bt, __ATOMIC_RELAXED,
                                  __HIP_MEMORY_SCOPE_AGENT);
        fastS = (__popc((unsigned)m) == 1);
    }
    __syncthreads();
    const bool fast = (fastS != 0);            // block-uniform

    // B fragments -> registers, once.
    bf16x8 bh[33], bx[9];
    if (wid < 3) {
        const bf16x8* bH = (const bf16x8*)whf + ((jblk * 3 + wid) * 33) * 64 + ln;
        #pragma unroll
        for (int kc = 0; kc < 33; ++kc) bh[kc] = bH[kc * 64];
        const bf16x8* bX = (const bf16x8*)wxf + ((jblk * 3 + wid) * 9) * 64 + ln;
        #pragma unroll
        for (int kc = 0; kc < 9; ++kc) bx[kc] = bX[kc * 64];
    }

    // Epilogue mapping: row br = tid>>3; cols j0 = 2*((tid&7)+8i), i in {0,1}.
    const int br = tid >> 3;
    const int lenb = lengths[b0 + br];
    float hreg[2][2];
    #pragma unroll
    for (int i = 0; i < 2; ++i) {
        int gj = jblk * 32 + 2 * ((tid & 7) + 8 * i);
        hreg[i][0] = __bfloat162float(h0p[(size_t)(b0 + br) * HKP + gj]);
        hreg[i][1] = __bfloat162float(h0p[(size_t)(b0 + br) * HKP + gj + 1]);
    }

    // x A-frags for t=0 + pre-computed x-part accumulator
    bf16x8 ax[9];
    f32x16 accX = {};
    if (wid < 3) {
        const bf16x8* aX = (const bf16x8*)(x16 + (size_t)row * XKP + khi);
        #pragma unroll
        for (int kc = 0; kc < 9; ++kc) ax[kc] = aX[kc * 2];
        #pragma unroll
        for (int kc = 0; kc < 9; ++kc)
            accX = __builtin_amdgcn_mfma_f32_32x32x16_bf16(ax[kc], bx[kc], accX, 0, 0, 0);
    }

    for (int t = 0; t < TT; ++t) {
        const __hip_bfloat16* hprev = (t == 0) ? h0p : (hist + (size_t)(t - 1) * BB * HKP);
        __hip_bfloat16* hout = hist + (size_t)t * BB * HKP;

        if (wid < 3) {
            f32x16 accHa = {}, accHb = {};
            const bf16x8* aH = (const bf16x8*)(hprev + (size_t)row * HKP + khi);
            #pragma unroll
            for (int kc = 0; kc < 32; kc += 2) {
                accHa = __builtin_amdgcn_mfma_f32_32x32x16_bf16(aH[kc * 2], bh[kc], accHa, 0, 0, 0);
                accHb = __builtin_amdgcn_mfma_f32_32x32x16_bf16(aH[(kc + 1) * 2], bh[kc + 1], accHb, 0, 0, 0);
            }
            accHa = __builtin_amdgcn_mfma_f32_32x32x16_bf16(aH[32 * 2], bh[32], accHa, 0, 0, 0);

            const int col = ln & 31;
            const int rh = 4 * (ln >> 5);
            if (wid < 2) {
                f32x16 s = accHa + accHb + accX;
                #pragma unroll
                for (int r = 0; r < 16; ++r)
                    p[wid][(r & 3) + 8 * (r >> 2) + rh][col] = s[r];
            } else {
                f32x16 sh = accHa + accHb;
                #pragma unroll
                for (int r = 0; r < 16; ++r) {
                    int rr = (r & 3) + 8 * (r >> 2) + rh;
                    p[2][rr][col] = accX[r];   // xn (+ b_ih_n)
                    p[3][rr][col] = sh[r];     // hn (+ b_hh_n)
                }
            }
        }
        __syncthreads();

        {   // gate epilogue: carry in registers, normal stores (L2)
            const bool valid = (t < lenb);
            #pragma unroll
            for (int i = 0; i < 2; ++i) {
                int j0 = 2 * ((tid & 7) + 8 * i);
                float rr0 = sigm(p[0][br][j0]);
                float zz0 = sigm(p[1][br][j0]);
                float nn0 = tanhf(p[2][br][j0] + rr0 * p[3][br][j0]);
                float h0v = valid ? ((1.f - zz0) * nn0 + zz0 * hreg[i][0]) : hreg[i][0];
                float rr1 = sigm(p[0][br][j0 + 1]);
                float zz1 = sigm(p[1][br][j0 + 1]);
                float nn1 = tanhf(p[2][br][j0 + 1] + rr1 * p[3][br][j0 + 1]);
                float h1v = valid ? ((1.f - zz1) * nn1 + zz1 * hreg[i][1]) : hreg[i][1];
                hreg[i][0] = h0v;
                hreg[i][1] = h1v;
                unsigned uv = (unsigned)bfbits(h0v) | ((unsigned)bfbits(h1v) << 16);
                *(unsigned*)(hout + (size_t)(b0 + br) * HKP + jblk * 32 + j0) = uv;
            }
        }
        __syncthreads();              // compiler drains vmcnt before s_barrier

        if (t < TT - 1) {
            if (tid == 0) {
                if (!fast) __threadfence();   // slow: wbl2 push (cross-XCD)
                __hip_atomic_store(myflag, t + 1, __ATOMIC_RELAXED, __HIP_MEMORY_SCOPE_AGENT);
            }
            if (wid < 3) {
                // overlap: prefetch x A-frags for t+1 and pre-compute x-part MFMAs
                const bf16x8* aX = (const bf16x8*)(x16 + ((size_t)(t + 1) * BB + row) * XKP + khi);
                #pragma unroll
                for (int kc = 0; kc < 9; ++kc) ax[kc] = aX[kc * 2];
                f32x16 aXn = {};
                #pragma unroll
                for (int kc = 0; kc < 9; ++kc)
                    aXn = __builtin_amdgcn_mfma_f32_32x32x16_bf16(ax[kc], bx[kc], aXn, 0, 0, 0);
                accX = aXn;
            }
            if (wid == 3) {           // idle wave polls the 16 group flags
                const int* f = flags + bt * 64 + (ln & 15);
                while (true) {
                    int v = __hip_atomic_load(f, __ATOMIC_RELAXED, __HIP_MEMORY_SCOPE_AGENT);
                    if (__all(v >= t + 1)) break;
                    __builtin_amdgcn_s_sleep(1);
                }
                if (!fast) __threadfence();   // slow: inv stale L1/L2 (cross-XCD)
            }
            __syncthreads();
        }
    }
}

// Write td into hist col 513 (after the scan) so the head's stage-1 is a pure
// K=528 GEMM over hist rows.
__global__ __launch_bounds__(256) void td_kernel(
    const float* __restrict__ x, __hip_bfloat16* __restrict__ hist)
{
    int r = blockIdx.x * 256 + threadIdx.x;
    if (r < RTOT) {
        int b = r / 255, t = r - b * 255;
        float td = x[((size_t)(t + 1) * BB + b) * DP1] - x[((size_t)t * BB + b) * DP1];
        hist[((size_t)t * BB + b) * HKP + 513] = __float2bfloat16(td);
    }
}

// MFMA head: block = 64 rows (2 row-tiles) x 4 waves, 1020 blocks.
__global__ __launch_bounds__(256) void head_mfma(
    const __hip_bfloat16* __restrict__ hist,
    const __hip_bfloat16* __restrict__ w1p,
    const __hip_bfloat16* __restrict__ w2p,
    const float* __restrict__ b2,
    const int* __restrict__ lengths,
    float* __restrict__ out)
{
    __shared__ __hip_bfloat16 preS[64 * 264];
    const int tid = threadIdx.x;
    const int wv  = tid >> 6;
    const int ln  = tid & 63;
    const int r0  = blockIdx.x * 64;
    const int m   = ln & 31;
    const int khi = (ln >> 5) * 8;

    const __hip_bfloat16* aBase0;
    const __hip_bfloat16* aBase1;
    {
        int r = r0 + m;
        int b = r / 255, t = r - b * 255;
        aBase0 = hist + ((size_t)t * BB + b) * HKP + khi;
        r = r0 + 32 + m;
        b = r / 255; t = r - b * 255;
        aBase1 = hist + ((size_t)t * BB + b) * HKP + khi;
    }

    f32x16 acc20 = {}, acc21 = {};

    for (int c = 0; c < 5; ++c) {
        f32x16 s00 = {}, s01 = {}, s10 = {}, s11 = {};
        const int t0 = c * 8 + wv * 2;
        const bf16x8* bp0 = (const bf16x8*)w1p + ((size_t)t0 * 33) * 64 + ln;
        const bf16x8* bp1 = bp0 + 33 * 64;
        #pragma unroll 4
        for (int kc = 0; kc < 33; ++kc) {
            bf16x8 a0 = *(const bf16x8*)(aBase0 + kc * 16);
            bf16x8 a1 = *(const bf16x8*)(aBase1 + kc * 16);
            bf16x8 w0 = bp0[kc * 64];
            bf16x8 w1f = bp1[kc * 64];
            s00 = __builtin_amdgcn_mfma_f32_32x32x16_bf16(a0, w0, s00, 0, 0, 0);
            s01 = __builtin_amdgcn_mfma_f32_32x32x16_bf16(a0, w1f, s01, 0, 0, 0);
            s10 = __builtin_amdgcn_mfma_f32_32x32x16_bf16(a1, w0, s10, 0, 0, 0);
            s11 = __builtin_amdgcn_mfma_f32_32x32x16_bf16(a1, w1f, s11, 0, 0, 0);
        }
        const int colL = wv * 64 + m;
        const int rb = 4 * (ln >> 5);
        #pragma unroll
        for (int reg = 0; reg < 16; ++reg) {
            int rr = (reg & 3) + 8 * (reg >> 2) + rb;
            preS[rr * 264 + colL]             = __float2bfloat16(sigm(s00[reg]));
            preS[rr * 264 + colL + 32]        = __float2bfloat16(sigm(s01[reg]));
            preS[(rr + 32) * 264 + colL]      = __float2bfloat16(sigm(s10[reg]));
            preS[(rr + 32) * 264 + colL + 32] = __float2bfloat16(sigm(s11[reg]));
        }
        __syncthreads();

        const bf16x8* b2p = (const bf16x8*)w2p + ((size_t)wv * 80 + c * 16) * 64 + ln;
        #pragma unroll 4
        for (int j = 0; j < 16; ++j) {
            bf16x8 pa0 = *(const bf16x8*)(preS + m * 264 + j * 16 + khi);
            bf16x8 pa1 = *(const bf16x8*)(preS + (32 + m) * 264 + j * 16 + khi);
            bf16x8 wb = b2p[j * 64];
            acc20 = __builtin_amdgcn_mfma_f32_32x32x16_bf16(pa0, wb, acc20, 0, 0, 0);
            acc21 = __builtin_amdgcn_mfma_f32_32x32x16_bf16(pa1, wb, acc21, 0, 0, 0);
        }
        __syncthreads();
    }

    const int d = wv * 32 + m;
    const float bias = b2[d];
    const int rb = 4 * (ln >> 5);
    #pragma unroll
    for (int reg = 0; reg < 16; ++reg) {
        int rr = (reg & 3) + 8 * (reg >> 2) + rb;
        {
            int r = r0 + rr;
            int b = r / 255, t = r - b * 255;
            bool valid = t < (lengths[b] - 1);
            out[(size_t)r * DD + d] = valid ? (acc20[reg] + bias) : 0.f;
        }
        {
            int r = r0 + 32 + rr;
            int b = r / 255, t = r - b * 255;
            bool valid = t < (lengths[b] - 1);
            out[(size_t)r * DD + d] = valid ? (acc21[reg] + bias) : 0.f;
        }
    }
}

__global__ __launch_bounds__(256) void tail_kernel(
    const __hip_bfloat16* __restrict__ hist,
    const float* __restrict__ wp,
    const float* __restrict__ bp,
    const int* __restrict__ lengths,
    float* __restrict__ out)
{
    int gid = blockIdx.x * 256 + threadIdx.x;
    if (gid < 768) {
        int b = gid / 3, pidx = gid - b * 3;
        float acc = bp[pidx];
        const __hip_bfloat16* hr = hist + ((size_t)(TT - 1) * BB + b) * HKP;
        const float* wr = wp + (size_t)pidx * HH;
        #pragma unroll 4
        for (int k = 0; k < HH; ++k) acc += __bfloat162float(hr[k]) * wr[k];
        out[OUT_DIST + gid] = __expf(-acc);
    } else if (gid < 1024) {
        int b = gid - 768;
        out[OUT_LEN + b] = (float)lengths[b];
    }
}

extern "C" void kernel_launch(void* const* d_in, const int* in_sizes, int n_in,
                              void* d_out, int out_size, void* d_ws, size_t ws_size,
                              hipStream_t stream)
{
    const float* x       = (const float*)d_in[0];
    const float* h0      = (const float*)d_in[1];
    const int*   lengths = (const int*)d_in[2];
    const float* w_ih    = (const float*)d_in[3];
    const float* w_hh    = (const float*)d_in[4];
    const float* b_ih    = (const float*)d_in[5];
    const float* b_hh    = (const float*)d_in[6];
    const float* w1      = (const float*)d_in[7];
    const float* b1      = (const float*)d_in[8];
    const float* w2      = (const float*)d_in[9];
    const float* b2      = (const float*)d_in[10];
    const float* wp      = (const float*)d_in[11];
    const float* bp      = (const float*)d_in[12];
    float* out = (float*)d_out;

    __hip_bfloat16* bf   = (__hip_bfloat16*)d_ws;
    __hip_bfloat16* x16  = bf + U_X16;
    __hip_bfloat16* whf  = bf + U_WHF;
    __hip_bfloat16* wxf  = bf + U_WXF;
    __hip_bfloat16* h16i = bf + U_H0;
    __hip_bfloat16* w1p  = bf + U_W1P;
    __hip_bfloat16* w2p  = bf + U_W2P;
    __hip_bfloat16* hist = bf + U_HIST;
    int* flags           = (int*)(bf + U_FLAGS);
    int* nego            = (int*)(bf + U_BAR);

    prep_kernel<<<PREP_N / 256, 256, 0, stream>>>(
        x, h0, w_ih, w_hh, b_ih, b_hh, w1, b1, w2, bf);

    gru_scan<<<dim3(8, 16), 256, 0, stream>>>(x16, h16i, hist, whf, wxf, lengths,
                                              flags, nego);

    td_kernel<<<(RTOT + 255) / 256, 256, 0, stream>>>(x, hist);

    head_mfma<<<RTOT / 64, 256, 0, stream>>>(hist, w1p, w2p, b2, lengths, out);

    tail_kernel<<<4, 256, 0, stream>>>(hist, wp, bp, lengths, out);
}

// Round 9
// 1958.064 us; speedup vs baseline: 1.5663x; 1.0960x over previous
//
#include <hip/hip_runtime.h>
#include <hip/hip_bf16.h>
#include <math.h>

#define TT 256
#define BB 256
#define DP1 129
#define HH 512
#define K1 1280
#define DD 128
#define RTOT 65280   // B*(T-1)
#define XKP 144      // padded x-part K (129 feats + 1 bias + 14 zero)
#define HKP 528      // padded h-part K (512 h + 1 bias@512 + td@513 + zeros)

// ---- ws layout: all bf16, base = (bf16*)ws ----
#define U_X16   0            // 65536*144
#define U_WHF   9437184      // 48*33*512
#define U_WXF   10248192     // 48*9*512
#define U_H0    10469376     // 256*528
#define U_BAR   10604544     // negotiation scratch: ints (zeroed each launch)
#define U_W1P   10604800     // 40 tiles * 33 kc * 512   (K=528, cols 1280)
#define U_W2P   11280640     // 4 tiles * 80 kc * 512    (K=1280, cols 128)
#define U_HIST  11444480     // 256*256*528
#define U_FLAGS 46047488     // 512 ints (8 groups x 64-int stride)
#define PREP_N  12494080     // total prep work items
// out layout (floats)
#define OUT_DIST 8355840     // 256*255*128
#define OUT_LEN  8356608

typedef __attribute__((ext_vector_type(8))) short bf16x8;
typedef __attribute__((ext_vector_type(16))) float f32x16;

__device__ __forceinline__ float sigm(float v) { return 1.0f / (1.0f + __expf(-v)); }

// branch-free tanh; clamp avoids exp overflow (tanh(+-20)==+-1 in fp32)
__device__ __forceinline__ float tanhfast(float x) {
    x = fminf(20.f, fmaxf(-20.f, x));
    float e = __expf(2.f * x);
    return (e - 1.f) / (e + 1.f);
}

__device__ __forceinline__ unsigned short bfbits(float f) {
    union { __hip_bfloat16 h; unsigned short u; } cv;
    cv.h = __float2bfloat16(f);
    return cv.u;
}

// One-time pack: bf16 x (+bias col), GRU weights as MFMA B-frags (biases folded
// as constant-1 K rows), h0, head weights as MFMA B-frags, hist pad columns
// (constant per step -> written once here), negotiation scratch + flag init.
__global__ __launch_bounds__(256) void prep_kernel(
    const float* __restrict__ x, const float* __restrict__ h0,
    const float* __restrict__ w_ih, const float* __restrict__ w_hh,
    const float* __restrict__ b_ih, const float* __restrict__ b_hh,
    const float* __restrict__ w1, const float* __restrict__ b1,
    const float* __restrict__ w2,
    __hip_bfloat16* __restrict__ bf)
{
    int i = blockIdx.x * 256 + threadIdx.x;
    if (i < 9437184) {                        // x16: (t*B+b, 144)
        int tb = i / XKP, k = i - tb * XKP;
        float v = (k < DP1) ? x[(size_t)tb * DP1 + k] : (k == DP1 ? 1.0f : 0.0f);
        bf[U_X16 + i] = __float2bfloat16(v);
    } else if (i < 10248192) {                // whf B-frags (K=528 incl b_hh row)
        int r = i - 9437184;
        int e = r & 7;
        int lane = (r >> 3) & 63;
        int rem = r >> 9;
        int kc = rem % 33, gi = rem / 33;
        int jb = gi / 3, g = gi - jb * 3;
        int j = jb * 32 + (lane & 31);
        int k = kc * 16 + (lane >> 5) * 8 + e;
        float v = (k < HH) ? w_hh[(size_t)(g * HH + j) * HH + k]
                : (k == HH ? b_hh[g * HH + j] : 0.0f);
        bf[U_WHF + r] = __float2bfloat16(v);
    } else if (i < 10469376) {                // wxf B-frags (K=144 incl b_ih row)
        int r = i - 10248192;
        int e = r & 7;
        int lane = (r >> 3) & 63;
        int rem = r >> 9;
        int kc = rem % 9, gi = rem / 9;
        int jb = gi / 3, g = gi - jb * 3;
        int j = jb * 32 + (lane & 31);
        int k = kc * 16 + (lane >> 5) * 8 + e;
        float v = (k < DP1) ? w_ih[(size_t)(g * HH + j) * DP1 + k]
                : (k == DP1 ? b_ih[g * HH + j] : 0.0f);
        bf[U_WXF + r] = __float2bfloat16(v);
    } else if (i < 10604544) {                // h0 padded (B, 528)
        int r = i - 10469376;
        int b = r / HKP, k = r - b * HKP;
        float v = (k < HH) ? h0[(size_t)b * HH + k] : (k == HH ? 1.0f : 0.0f);
        bf[U_H0 + r] = __float2bfloat16(v);
    } else if (i < 10604800) {                // zero negotiation scratch
        bf[U_BAR + (i - 10604544)] = __float2bfloat16(0.0f);
    } else if (i < 11280640) {                // w1p B-frags (40 tiles, 33 kc)
        int r = i - 10604800;
        int e = r & 7;
        int lane = (r >> 3) & 63;
        int rem = r >> 9;
        int kc = rem % 33, tile = rem / 33;
        int col = tile * 32 + (lane & 31);
        int k = kc * 16 + (lane >> 5) * 8 + e;
        float v = (k < HH) ? w1[(size_t)col * 513 + k]
                : (k == HH ? b1[col]
                : (k == HH + 1 ? w1[(size_t)col * 513 + 512] : 0.0f));
        bf[U_W1P + r] = __float2bfloat16(v);
    } else if (i < 11444480) {                // w2p B-frags (4 tiles, 80 kc)
        int r = i - 11280640;
        int e = r & 7;
        int lane = (r >> 3) & 63;
        int rem = r >> 9;
        int kc = rem % 80, tile = rem / 80;
        int col = tile * 32 + (lane & 31);
        int k = kc * 16 + (lane >> 5) * 8 + e;
        bf[U_W2P + r] = __float2bfloat16(w2[(size_t)col * K1 + k]);
    } else if (i < 12493056) {                // hist pad cols 512..527, all (t,b)
        int idx = i - 11444480;
        int row = idx >> 4, c = idx & 15;
        bf[U_HIST + (size_t)row * HKP + HH + c] =
            __float2bfloat16(c == 0 ? 1.0f : 0.0f);
    } else if (i < PREP_N) {                  // zero flags (ws is re-poisoned!)
        int idx = i - 12493056;
        if (idx < 512) ((int*)(bf + U_FLAGS))[idx] = 0;
    }
}

// Persistent GRU scan. Grid (8 bt, 16 jblk) = 128 blocks, 256 thr, all
// co-resident. Waves 0/1/2 = gates r/z/n, B-frags + h carry in registers.
//
// Cross-block sync per step, runtime-selected:
//  * FAST (group's 16 blocks on ONE XCD, via HW_REG_XCC_ID + LLC mask
//    exchange): h stores drain into the shared XCD-L2 at __syncthreads;
//    flag = PLAIN global store (lands in same L2); poll = sc0 loads
//    (L1-bypass, L2-hit). No LLC, no fences. Each compute wave polls for
//    itself after pre-computing the next x-part -> only 2 barriers/step.
//  * SLOW (group spans XCDs): round-7 proven protocol — __threadfence
//    release + agent-scope flag store / agent poll + __threadfence acquire.
__global__ __launch_bounds__(256, 1) void gru_scan(
    const __hip_bfloat16* __restrict__ x16,
    const __hip_bfloat16* __restrict__ h0p,
    __hip_bfloat16* __restrict__ hist,
    const __hip_bfloat16* __restrict__ whf,
    const __hip_bfloat16* __restrict__ wxf,
    const int* __restrict__ lengths,
    int* __restrict__ flags,
    int* __restrict__ nego)
{
    __shared__ float p[4][32][33];
    __shared__ int fastS;
    const int tid  = threadIdx.x;
    const int bt   = blockIdx.x;
    const int jblk = blockIdx.y;
    const int b0   = bt * 32;
    const int wid  = tid >> 6;
    const int ln   = tid & 63;
    const int row  = b0 + (ln & 31);
    const int khi  = (ln >> 5) * 8;
    int* myflag = flags + bt * 64 + jblk;

    // --- one-time group topology negotiation (through LLC) ---
    if (tid == 0) {
        int xcc = 0;
        asm volatile("s_getreg_b32 %0, hwreg(HW_REG_XCC_ID, 0, 32)" : "=s"(xcc));
        atomicOr(nego + bt, 1 << (xcc & 7));
        __threadfence();                       // order OR before arrive
        atomicAdd(nego + 8 + bt, 1);
        while (__hip_atomic_load(nego + 8 + bt, __ATOMIC_RELAXED,
                                 __HIP_MEMORY_SCOPE_AGENT) < 16)
            __builtin_amdgcn_s_sleep(1);
        int m = __hip_atomic_load(nego + bt, __ATOMIC_RELAXED,
                                  __HIP_MEMORY_SCOPE_AGENT);
        fastS = (__popc((unsigned)m) == 1);
    }
    __syncthreads();
    const bool fast = (fastS != 0);            // block-uniform

    // B fragments -> registers, once.
    bf16x8 bh[33], bx[9];
    if (wid < 3) {
        const bf16x8* bH = (const bf16x8*)whf + ((jblk * 3 + wid) * 33) * 64 + ln;
        #pragma unroll
        for (int kc = 0; kc < 33; ++kc) bh[kc] = bH[kc * 64];
        const bf16x8* bX = (const bf16x8*)wxf + ((jblk * 3 + wid) * 9) * 64 + ln;
        #pragma unroll
        for (int kc = 0; kc < 9; ++kc) bx[kc] = bX[kc * 64];
    }

    // Epilogue mapping: row br = tid>>3; cols j0 = 2*((tid&7)+8i), i in {0,1}.
    const int br = tid >> 3;
    const int lenb = lengths[b0 + br];
    float hreg[2][2];
    #pragma unroll
    for (int i = 0; i < 2; ++i) {
        int gj = jblk * 32 + 2 * ((tid & 7) + 8 * i);
        hreg[i][0] = __bfloat162float(h0p[(size_t)(b0 + br) * HKP + gj]);
        hreg[i][1] = __bfloat162float(h0p[(size_t)(b0 + br) * HKP + gj + 1]);
    }

    // x A-frags for t=0 + pre-computed x-part accumulator
    bf16x8 ax[9];
    f32x16 accX = {};
    if (wid < 3) {
        const bf16x8* aX = (const bf16x8*)(x16 + (size_t)row * XKP + khi);
        #pragma unroll
        for (int kc = 0; kc < 9; ++kc) ax[kc] = aX[kc * 2];
        #pragma unroll
        for (int kc = 0; kc < 9; ++kc)
            accX = __builtin_amdgcn_mfma_f32_32x32x16_bf16(ax[kc], bx[kc], accX, 0, 0, 0);
    }

    for (int t = 0; t < TT; ++t) {
        const __hip_bfloat16* hprev = (t == 0) ? h0p : (hist + (size_t)(t - 1) * BB * HKP);
        __hip_bfloat16* hout = hist + (size_t)t * BB * HKP;

        if (wid < 3) {
            f32x16 accHa = {}, accHb = {};
            const bf16x8* aH = (const bf16x8*)(hprev + (size_t)row * HKP + khi);
            #pragma unroll
            for (int kc = 0; kc < 32; kc += 2) {
                accHa = __builtin_amdgcn_mfma_f32_32x32x16_bf16(aH[kc * 2], bh[kc], accHa, 0, 0, 0);
                accHb = __builtin_amdgcn_mfma_f32_32x32x16_bf16(aH[(kc + 1) * 2], bh[kc + 1], accHb, 0, 0, 0);
            }
            accHa = __builtin_amdgcn_mfma_f32_32x32x16_bf16(aH[32 * 2], bh[32], accHa, 0, 0, 0);

            const int col = ln & 31;
            const int rh = 4 * (ln >> 5);
            if (wid < 2) {
                f32x16 s = accHa + accHb + accX;
                #pragma unroll
                for (int r = 0; r < 16; ++r)
                    p[wid][(r & 3) + 8 * (r >> 2) + rh][col] = s[r];
            } else {
                f32x16 sh = accHa + accHb;
                #pragma unroll
                for (int r = 0; r < 16; ++r) {
                    int rr = (r & 3) + 8 * (r >> 2) + rh;
                    p[2][rr][col] = accX[r];   // xn (+ b_ih_n)
                    p[3][rr][col] = sh[r];     // hn (+ b_hh_n)
                }
            }
        }
        __syncthreads();

        {   // gate epilogue: carry in registers, normal stores (L2)
            const bool valid = (t < lenb);
            #pragma unroll
            for (int i = 0; i < 2; ++i) {
                int j0 = 2 * ((tid & 7) + 8 * i);
                float rr0 = sigm(p[0][br][j0]);
                float zz0 = sigm(p[1][br][j0]);
                float nn0 = tanhfast(p[2][br][j0] + rr0 * p[3][br][j0]);
                float h0v = valid ? ((1.f - zz0) * nn0 + zz0 * hreg[i][0]) : hreg[i][0];
                float rr1 = sigm(p[0][br][j0 + 1]);
                float zz1 = sigm(p[1][br][j0 + 1]);
                float nn1 = tanhfast(p[2][br][j0 + 1] + rr1 * p[3][br][j0 + 1]);
                float h1v = valid ? ((1.f - zz1) * nn1 + zz1 * hreg[i][1]) : hreg[i][1];
                hreg[i][0] = h0v;
                hreg[i][1] = h1v;
                unsigned uv = (unsigned)bfbits(h0v) | ((unsigned)bfbits(h1v) << 16);
                *(unsigned*)(hout + (size_t)(b0 + br) * HKP + jblk * 32 + j0) = uv;
            }
        }
        __syncthreads();              // drains vmcnt: all h stores at L2

        if (t < TT - 1) {
            if (tid == 0) {
                if (fast) {
                    int tv = t + 1;
                    asm volatile("global_store_dword %0, %1, off"
                                 :: "v"(myflag), "v"(tv) : "memory");
                } else {
                    __threadfence();  // slow: wbl2 push (cross-XCD)
                    __hip_atomic_store(myflag, t + 1, __ATOMIC_RELAXED,
                                       __HIP_MEMORY_SCOPE_AGENT);
                }
            }
            if (wid < 3) {
                // overlap flag latency: prefetch x A-frags for t+1 and
                // pre-compute the x-part MFMAs (h-independent)
                const bf16x8* aX = (const bf16x8*)(x16 + ((size_t)(t + 1) * BB + row) * XKP + khi);
                #pragma unroll
                for (int kc = 0; kc < 9; ++kc) ax[kc] = aX[kc * 2];
                f32x16 aXn = {};
                #pragma unroll
                for (int kc = 0; kc < 9; ++kc)
                    aXn = __builtin_amdgcn_mfma_f32_32x32x16_bf16(ax[kc], bx[kc], aXn, 0, 0, 0);
                accX = aXn;

                // each compute wave polls for itself (no extra barrier; wave 3
                // only touches p after the next sync, so it need not poll)
                const int* f = flags + bt * 64 + (ln & 15);
                if (fast) {
                    while (true) {
                        int v;
                        asm volatile("global_load_dword %0, %1, off sc0\n\t"
                                     "s_waitcnt vmcnt(0)"
                                     : "=v"(v) : "v"(f) : "memory");
                        if (__all(v >= t + 1)) break;
                        __builtin_amdgcn_s_sleep(1);
                    }
                } else {
                    while (true) {
                        int v = __hip_atomic_load(f, __ATOMIC_RELAXED,
                                                  __HIP_MEMORY_SCOPE_AGENT);
                        if (__all(v >= t + 1)) break;
                        __builtin_amdgcn_s_sleep(1);
                    }
                    __threadfence();  // slow: inv stale L1/L2 (cross-XCD)
                }
            }
        }
    }
}

// Write td into hist col 513 (after the scan) so the head's stage-1 is a pure
// K=528 GEMM over hist rows.
__global__ __launch_bounds__(256) void td_kernel(
    const float* __restrict__ x, __hip_bfloat16* __restrict__ hist)
{
    int r = blockIdx.x * 256 + threadIdx.x;
    if (r < RTOT) {
        int b = r / 255, t = r - b * 255;
        float td = x[((size_t)(t + 1) * BB + b) * DP1] - x[((size_t)t * BB + b) * DP1];
        hist[((size_t)t * BB + b) * HKP + 513] = __float2bfloat16(td);
    }
}

// MFMA head: block = 64 rows (2 row-tiles) x 4 waves, 1020 blocks.
__global__ __launch_bounds__(256) void head_mfma(
    const __hip_bfloat16* __restrict__ hist,
    const __hip_bfloat16* __restrict__ w1p,
    const __hip_bfloat16* __restrict__ w2p,
    const float* __restrict__ b2,
    const int* __restrict__ lengths,
    float* __restrict__ out)
{
    __shared__ __hip_bfloat16 preS[64 * 264];
    const int tid = threadIdx.x;
    const int wv  = tid >> 6;
    const int ln  = tid & 63;
    const int r0  = blockIdx.x * 64;
    const int m   = ln & 31;
    const int khi = (ln >> 5) * 8;

    const __hip_bfloat16* aBase0;
    const __hip_bfloat16* aBase1;
    {
        int r = r0 + m;
        int b = r / 255, t = r - b * 255;
        aBase0 = hist + ((size_t)t * BB + b) * HKP + khi;
        r = r0 + 32 + m;
        b = r / 255; t = r - b * 255;
        aBase1 = hist + ((size_t)t * BB + b) * HKP + khi;
    }

    f32x16 acc20 = {}, acc21 = {};

    for (int c = 0; c < 5; ++c) {
        f32x16 s00 = {}, s01 = {}, s10 = {}, s11 = {};
        const int t0 = c * 8 + wv * 2;
        const bf16x8* bp0 = (const bf16x8*)w1p + ((size_t)t0 * 33) * 64 + ln;
        const bf16x8* bp1 = bp0 + 33 * 64;
        #pragma unroll 4
        for (int kc = 0; kc < 33; ++kc) {
            bf16x8 a0 = *(const bf16x8*)(aBase0 + kc * 16);
            bf16x8 a1 = *(const bf16x8*)(aBase1 + kc * 16);
            bf16x8 w0 = bp0[kc * 64];
            bf16x8 w1f = bp1[kc * 64];
            s00 = __builtin_amdgcn_mfma_f32_32x32x16_bf16(a0, w0, s00, 0, 0, 0);
            s01 = __builtin_amdgcn_mfma_f32_32x32x16_bf16(a0, w1f, s01, 0, 0, 0);
            s10 = __builtin_amdgcn_mfma_f32_32x32x16_bf16(a1, w0, s10, 0, 0, 0);
            s11 = __builtin_amdgcn_mfma_f32_32x32x16_bf16(a1, w1f, s11, 0, 0, 0);
        }
        const int colL = wv * 64 + m;
        const int rb = 4 * (ln >> 5);
        #pragma unroll
        for (int reg = 0; reg < 16; ++reg) {
            int rr = (reg & 3) + 8 * (reg >> 2) + rb;
            preS[rr * 264 + colL]             = __float2bfloat16(sigm(s00[reg]));
            preS[rr * 264 + colL + 32]        = __float2bfloat16(sigm(s01[reg]));
            preS[(rr + 32) * 264 + colL]      = __float2bfloat16(sigm(s10[reg]));
            preS[(rr + 32) * 264 + colL + 32] = __float2bfloat16(sigm(s11[reg]));
        }
        __syncthreads();

        const bf16x8* b2p = (const bf16x8*)w2p + ((size_t)wv * 80 + c * 16) * 64 + ln;
        #pragma unroll 4
        for (int j = 0; j < 16; ++j) {
            bf16x8 pa0 = *(const bf16x8*)(preS + m * 264 + j * 16 + khi);
            bf16x8 pa1 = *(const bf16x8*)(preS + (32 + m) * 264 + j * 16 + khi);
            bf16x8 wb = b2p[j * 64];
            acc20 = __builtin_amdgcn_mfma_f32_32x32x16_bf16(pa0, wb, acc20, 0, 0, 0);
            acc21 = __builtin_amdgcn_mfma_f32_32x32x16_bf16(pa1, wb, acc21, 0, 0, 0);
        }
        __syncthreads();
    }

    const int d = wv * 32 + m;
    const float bias = b2[d];
    const int rb = 4 * (ln >> 5);
    #pragma unroll
    for (int reg = 0; reg < 16; ++reg) {
        int rr = (reg & 3) + 8 * (reg >> 2) + rb;
        {
            int r = r0 + rr;
            int b = r / 255, t = r - b * 255;
            bool valid = t < (lengths[b] - 1);
            out[(size_t)r * DD + d] = valid ? (acc20[reg] + bias) : 0.f;
        }
        {
            int r = r0 + 32 + rr;
            int b = r / 255, t = r - b * 255;
            bool valid = t < (lengths[b] - 1);
            out[(size_t)r * DD + d] = valid ? (acc21[reg] + bias) : 0.f;
        }
    }
}

__global__ __launch_bounds__(256) void tail_kernel(
    const __hip_bfloat16* __restrict__ hist,
    const float* __restrict__ wp,
    const float* __restrict__ bp,
    const int* __restrict__ lengths,
    float* __restrict__ out)
{
    int gid = blockIdx.x * 256 + threadIdx.x;
    if (gid < 768) {
        int b = gid / 3, pidx = gid - b * 3;
        float acc = bp[pidx];
        const __hip_bfloat16* hr = hist + ((size_t)(TT - 1) * BB + b) * HKP;
        const float* wr = wp + (size_t)pidx * HH;
        #pragma unroll 4
        for (int k = 0; k < HH; ++k) acc += __bfloat162float(hr[k]) * wr[k];
        out[OUT_DIST + gid] = __expf(-acc);
    } else if (gid < 1024) {
        int b = gid - 768;
        out[OUT_LEN + b] = (float)lengths[b];
    }
}

extern "C" void kernel_launch(void* const* d_in, const int* in_sizes, int n_in,
                              void* d_out, int out_size, void* d_ws, size_t ws_size,
                              hipStream_t stream)
{
    const float* x       = (const float*)d_in[0];
    const float* h0      = (const float*)d_in[1];
    const int*   lengths = (const int*)d_in[2];
    const float* w_ih    = (const float*)d_in[3];
    const float* w_hh    = (const float*)d_in[4];
    const float* b_ih    = (const float*)d_in[5];
    const float* b_hh    = (const float*)d_in[6];
    const float* w1      = (const float*)d_in[7];
    const float* b1      = (const float*)d_in[8];
    const float* w2      = (const float*)d_in[9];
    const float* b2      = (const float*)d_in[10];
    const float* wp      = (const float*)d_in[11];
    const float* bp      = (const float*)d_in[12];
    float* out = (float*)d_out;

    __hip_bfloat16* bf   = (__hip_bfloat16*)d_ws;
    __hip_bfloat16* x16  = bf + U_X16;
    __hip_bfloat16* whf  = bf + U_WHF;
    __hip_bfloat16* wxf  = bf + U_WXF;
    __hip_bfloat16* h16i = bf + U_H0;
    __hip_bfloat16* w1p  = bf + U_W1P;
    __hip_bfloat16* w2p  = bf + U_W2P;
    __hip_bfloat16* hist = bf + U_HIST;
    int* flags           = (int*)(bf + U_FLAGS);
    int* nego            = (int*)(bf + U_BAR);

    prep_kernel<<<PREP_N / 256, 256, 0, stream>>>(
        x, h0, w_ih, w_hh, b_ih, b_hh, w1, b1, w2, bf);

    gru_scan<<<dim3(8, 16), 256, 0, stream>>>(x16, h16i, hist, whf, wxf, lengths,
                                              flags, nego);

    td_kernel<<<(RTOT + 255) / 256, 256, 0, stream>>>(x, hist);

    head_mfma<<<RTOT / 64, 256, 0, stream>>>(hist, w1p, w2p, b2, lengths, out);

    tail_kernel<<<4, 256, 0, stream>>>(hist, wp, bp, lengths, out);
}